// Round 1
// baseline (266.141 us; speedup 1.0000x reference)
//
#include <hip/hip_runtime.h>
#include <hip/hip_bf16.h>

#define N_ROWS 16384
#define M_ROWS 16384
#define DIM 256

typedef __attribute__((ext_vector_type(4))) float f32x4;
typedef __attribute__((ext_vector_type(8))) short bf16x8;

__device__ inline unsigned enc_f(float f) {
  unsigned u = __float_as_uint(f);
  return (u & 0x80000000u) ? ~u : (u | 0x80000000u);
}
__device__ inline float dec_f(unsigned u) {
  unsigned b = (u & 0x80000000u) ? (u & 0x7FFFFFFFu) : ~u;
  return __uint_as_float(b);
}
__device__ inline unsigned short f2bf(float f) {
  unsigned u = __float_as_uint(f);
  u += 0x7FFFu + ((u >> 16) & 1u);
  return (unsigned short)(u >> 16);
}

// Convert one fp32 row block to bf16, compute row sum-of-squares (minus psi if given).
// Block = 256 threads = 4 waves; each wave handles one row of 256 elements.
__global__ __launch_bounds__(256) void prep_kernel(
    const float* __restrict__ in, unsigned short* __restrict__ outb,
    float* __restrict__ out2, const float* __restrict__ psi) {
  int row  = blockIdx.x * 4 + (threadIdx.x >> 6);
  int lane = threadIdx.x & 63;
  const float4 v = *reinterpret_cast<const float4*>(in + (size_t)row * DIM + lane * 4);
  ushort4 b;
  b.x = f2bf(v.x); b.y = f2bf(v.y); b.z = f2bf(v.z); b.w = f2bf(v.w);
  *reinterpret_cast<ushort4*>(outb + (size_t)row * DIM + lane * 4) = b;
  float s = v.x * v.x + v.y * v.y + v.z * v.z + v.w * v.w;
#pragma unroll
  for (int m = 1; m < 64; m <<= 1) s += __shfl_xor(s, m, 64);
  if (lane == 0) out2[row] = psi ? (s - psi[row]) : s;
}

__global__ __launch_bounds__(256) void psimean_kernel(
    const float* __restrict__ psi, float* __restrict__ out) {
  int tid = threadIdx.x;
  double s = 0.0;
  for (int i = tid; i < M_ROWS; i += 256) s += (double)psi[i];
  __shared__ double sm[4];
#pragma unroll
  for (int m = 1; m < 64; m <<= 1) s += __shfl_xor(s, m, 64);
  if ((tid & 63) == 0) sm[tid >> 6] = s;
  __syncthreads();
  if (tid == 0) out[1] = (float)((sm[0] + sm[1] + sm[2] + sm[3]) / (double)M_ROWS);
}

// 128x128 bf16 MFMA tile, fused (r[j] - 2*dot) row-min epilogue.
__global__ __launch_bounds__(256, 2) void gemm_min_kernel(
    const unsigned short* __restrict__ xb, const unsigned short* __restrict__ yb,
    const float* __restrict__ rj, unsigned int* __restrict__ rowmin) {
  __shared__ unsigned short Atile[128 * 64];
  __shared__ unsigned short Btile[128 * 64];
  __shared__ float minbuf[128][2];

  // XCD-chunked swizzle (8 XCDs, 16384 blocks) + 16x16-tile supertiles:
  // each XCD runs 8 supertiles; each supertile touches 16 x-tiles + 16 y-tiles (~2MB, L2-fit).
  int bid     = blockIdx.x;
  int logical = (bid & 7) * 2048 + (bid >> 3);
  int st      = logical >> 8;
  int within  = logical & 255;
  int bi = (st >> 3) * 16 + (within >> 4);
  int bj = (st & 7) * 16 + (within & 15);
  int brow = bi * 128, bcol = bj * 128;

  int tid = threadIdx.x;
  int wid = tid >> 6, lane = tid & 63;
  int wr = wid >> 1, wc = wid & 1;  // 2x2 wave grid, 64x64 output per wave

  f32x4 acc[4][4];
#pragma unroll
  for (int i = 0; i < 4; ++i)
#pragma unroll
    for (int j = 0; j < 4; ++j) acc[i][j] = (f32x4){0.f, 0.f, 0.f, 0.f};

  // staging: each wave stages 32 rows of A and B per K-chunk; one global_load_lds
  // moves 64 lanes x 16B = 8 rows x 64 cols (LDS dest is wave-uniform base + lane*16).
  const int sr = lane >> 3;        // row within 8-row chunk
  const int sc = (lane & 7) * 8;   // col within 64
  const unsigned short* gA = xb + (size_t)(brow + wid * 32 + sr) * DIM + sc;
  const unsigned short* gB = yb + (size_t)(bcol + wid * 32 + sr) * DIM + sc;
  unsigned short* lA = &Atile[(wid * 32) * 64];
  unsigned short* lB = &Btile[(wid * 32) * 64];

  // MFMA fragment addressing (16x16x32 bf16): row = lane&15, k = (lane>>4)*8 .. +8
  const int fr = lane & 15;
  const int fk = (lane >> 4) * 8;

  for (int kt = 0; kt < 4; ++kt) {
#pragma unroll
    for (int c = 0; c < 4; ++c) {
      __builtin_amdgcn_global_load_lds(
          (const __attribute__((address_space(1))) void*)(gA + (size_t)c * 8 * DIM + kt * 64),
          (__attribute__((address_space(3))) void*)(lA + c * 8 * 64), 16, 0, 0);
      __builtin_amdgcn_global_load_lds(
          (const __attribute__((address_space(1))) void*)(gB + (size_t)c * 8 * DIM + kt * 64),
          (__attribute__((address_space(3))) void*)(lB + c * 8 * 64), 16, 0, 0);
    }
    asm volatile("s_waitcnt vmcnt(0)" ::: "memory");
    __syncthreads();
#pragma unroll
    for (int kk = 0; kk < 2; ++kk) {
      bf16x8 afr[4], bfr[4];
#pragma unroll
      for (int mi = 0; mi < 4; ++mi)
        afr[mi] = *reinterpret_cast<const bf16x8*>(
            &Atile[(wr * 64 + mi * 16 + fr) * 64 + kk * 32 + fk]);
#pragma unroll
      for (int ni = 0; ni < 4; ++ni)
        bfr[ni] = *reinterpret_cast<const bf16x8*>(
            &Btile[(wc * 64 + ni * 16 + fr) * 64 + kk * 32 + fk]);
#pragma unroll
      for (int mi = 0; mi < 4; ++mi)
#pragma unroll
        for (int ni = 0; ni < 4; ++ni)
          acc[mi][ni] = __builtin_amdgcn_mfma_f32_16x16x32_bf16(
              afr[mi], bfr[ni], acc[mi][ni], 0, 0, 0);
    }
    __syncthreads();
  }

  // Epilogue: val = r[j] - 2*dot; min over this block's 128 columns.
  // C/D layout: col = lane&15, row = (lane>>4)*4 + reg (m89-verified).
  float rv[4];
#pragma unroll
  for (int ni = 0; ni < 4; ++ni) rv[ni] = rj[bcol + wc * 64 + ni * 16 + fr];

#pragma unroll
  for (int mi = 0; mi < 4; ++mi) {
#pragma unroll
    for (int r = 0; r < 4; ++r) {
      float m = rv[0] - 2.f * acc[mi][0][r];
#pragma unroll
      for (int ni = 1; ni < 4; ++ni) m = fminf(m, rv[ni] - 2.f * acc[mi][ni][r]);
#pragma unroll
      for (int s = 1; s < 16; s <<= 1) m = fminf(m, __shfl_xor(m, s, 64));
      if (fr == 0) minbuf[wr * 64 + mi * 16 + (lane >> 4) * 4 + r][wc] = m;
    }
  }
  __syncthreads();
  if (tid < 128) {
    float v = fminf(minbuf[tid][0], minbuf[tid][1]);
    atomicMin(&rowmin[brow + tid], enc_f(v));
  }
}

__global__ __launch_bounds__(256) void finish_kernel(
    const float* __restrict__ x2, const unsigned int* __restrict__ rowmin,
    float* __restrict__ out) {
  int tid = threadIdx.x;
  double s = 0.0;
  for (int i = tid; i < N_ROWS; i += 256)
    s += (double)x2[i] + (double)dec_f(rowmin[i]);
  __shared__ double sm[4];
#pragma unroll
  for (int m = 1; m < 64; m <<= 1) s += __shfl_xor(s, m, 64);
  if ((tid & 63) == 0) sm[tid >> 6] = s;
  __syncthreads();
  if (tid == 0) out[0] = (float)((sm[0] + sm[1] + sm[2] + sm[3]) / (double)N_ROWS);
}

extern "C" void kernel_launch(void* const* d_in, const int* in_sizes, int n_in,
                              void* d_out, int out_size, void* d_ws, size_t ws_size,
                              hipStream_t stream) {
  const float* x   = (const float*)d_in[0];
  const float* y   = (const float*)d_in[1];
  const float* psi = (const float*)d_in[2];
  float* out = (float*)d_out;

  char* ws = (char*)d_ws;
  unsigned short* xb = (unsigned short*)ws;                                  // 8 MB
  unsigned short* yb = (unsigned short*)(ws + (size_t)N_ROWS * DIM * 2);     // 8 MB
  float* x2 = (float*)(ws + (size_t)(N_ROWS + M_ROWS) * DIM * 2);            // 64 KB
  float* rj = x2 + N_ROWS;                                                   // 64 KB (y2 - psi)
  unsigned int* rowmin = (unsigned int*)(rj + M_ROWS);                       // 64 KB

  prep_kernel<<<N_ROWS / 4, 256, 0, stream>>>(x, xb, x2, nullptr);
  prep_kernel<<<M_ROWS / 4, 256, 0, stream>>>(y, yb, rj, psi);
  psimean_kernel<<<1, 256, 0, stream>>>(psi, out);
  hipMemsetAsync(rowmin, 0xFF, N_ROWS * sizeof(unsigned int), stream);
  gemm_min_kernel<<<(N_ROWS / 128) * (M_ROWS / 128), 256, 0, stream>>>(xb, yb, rj, rowmin);
  finish_kernel<<<1, 256, 0, stream>>>(x2, rowmin, out);
}